// Round 4
// baseline (461.574 us; speedup 1.0000x reference)
//
#include <hip/hip_runtime.h>
#include <cstdint>
#include <cstddef>

#define NT 256
#define DFEAT 128
#define SCAN_ELEMS 1024
#define GEMM_ROWS 128    // rows per gemm block (4 waves x 32 rows)
#define CTRL_FLAG 0x40000000
#define SRC_MASK  0x3fffffff

typedef __attribute__((ext_vector_type(8))) short s8v;
typedef __attribute__((ext_vector_type(4))) float f32x4;

__device__ inline ushort f2bf(float f) {           // RNE fp32 -> bf16
  uint32_t u = __float_as_uint(f);
  u += 0x7fffu + ((u >> 16) & 1u);
  return (ushort)(u >> 16);
}

// ---------- zero int array ----------
__global__ void zero_k(int* __restrict__ p, int n) {
  int i = blockIdx.x * NT + threadIdx.x;
  if (i < n) p[i] = 0;
}

// ---------- histogram of dst, both graphs in one dispatch ----------
__global__ void hist2_k(const int* __restrict__ e_dst, int E,
                        const int* __restrict__ c_dst, int EC,
                        int* __restrict__ cnt_c, int* __restrict__ cnt_t) {
  int i = blockIdx.x * NT + threadIdx.x;
  if (i < E) atomicAdd(&cnt_c[e_dst[i]], 1);
  else if (i < E + EC) atomicAdd(&cnt_t[c_dst[i - E]], 1);
}

// ---------- dinv_all[0..n) = conv, [n..2n) = ctrl (from histogram counts) ----------
__global__ void dinv2_k(const int* __restrict__ cntc, const int* __restrict__ cntt,
                        float* __restrict__ dall, int n) {
  int i = blockIdx.x * NT + threadIdx.x;
  if (i < n) {
    dall[i]     = rsqrtf((float)(cntc[i] + 1));
    dall[n + i] = rsqrtf((float)(cntt[i] + 1));
  }
}

// ---------- merged scan pass A: per-block sums of (cnt_c + cnt_t) ----------
__global__ __launch_bounds__(NT) void scan_partial_m(
    const int* __restrict__ cnt_c, const int* __restrict__ cnt_t, int n,
    int* __restrict__ bsum) {
  int base = blockIdx.x * SCAN_ELEMS + threadIdx.x * 4;
  int s = 0;
  if (base + 3 < n) {
    int4 a = *(const int4*)&cnt_c[base];
    int4 b = *(const int4*)&cnt_t[base];
    s = a.x + a.y + a.z + a.w + b.x + b.y + b.z + b.w;
  } else {
    for (int j = 0; j < 4; j++) if (base + j < n) s += cnt_c[base + j] + cnt_t[base + j];
  }
  for (int off = 32; off > 0; off >>= 1) s += __shfl_down(s, off, 64);
  __shared__ int ws[4];
  int lane = threadIdx.x & 63, w = threadIdx.x >> 6;
  if (lane == 0) ws[w] = s;
  __syncthreads();
  if (threadIdx.x == 0) bsum[blockIdx.x] = ws[0] + ws[1] + ws[2] + ws[3];
}

// ---------- merged scan pass B: exclusive prefix over block sums ----------
__global__ __launch_bounds__(NT) void scan_offsets_m(
    int* __restrict__ bsum, int nb, int* __restrict__ rp, int n) {
  __shared__ int ls[NT];
  int t = threadIdx.x;
  int v = (t < nb) ? bsum[t] : 0;
  ls[t] = v;
  __syncthreads();
  for (int off = 1; off < NT; off <<= 1) {
    int u = (t >= off) ? ls[t - off] : 0;
    __syncthreads();
    ls[t] += u;
    __syncthreads();
  }
  if (t < nb) bsum[t] = ls[t] - v;
  if (t == nb - 1) rp[n] = ls[t];
}

// ---------- merged scan pass C: rowptr + cursor (cnt_c becomes fill cursor) ----------
__global__ __launch_bounds__(NT) void scan_final_m(
    int* __restrict__ cnt_c, const int* __restrict__ cnt_t, int n,
    const int* __restrict__ bsum, int* __restrict__ rp) {
  int offset = bsum[blockIdx.x];
  int base = blockIdx.x * SCAN_ELEMS + threadIdx.x * 4;

  int4 v = make_int4(0, 0, 0, 0);
  if (base + 3 < n) {
    int4 a = *(const int4*)&cnt_c[base];
    int4 b = *(const int4*)&cnt_t[base];
    v = make_int4(a.x + b.x, a.y + b.y, a.z + b.z, a.w + b.w);
  } else {
    if (base + 0 < n) v.x = cnt_c[base + 0] + cnt_t[base + 0];
    if (base + 1 < n) v.y = cnt_c[base + 1] + cnt_t[base + 1];
    if (base + 2 < n) v.z = cnt_c[base + 2] + cnt_t[base + 2];
    if (base + 3 < n) v.w = cnt_c[base + 3] + cnt_t[base + 3];
  }
  int tsum = v.x + v.y + v.z + v.w;

  __shared__ int ls[NT];
  int t = threadIdx.x;
  ls[t] = tsum;
  __syncthreads();
  for (int off = 1; off < NT; off <<= 1) {
    int u = (t >= off) ? ls[t - off] : 0;
    __syncthreads();
    ls[t] += u;
    __syncthreads();
  }
  int excl = offset + ls[t] - tsum;

  int4 o;
  o.x = excl;
  o.y = o.x + v.x;
  o.z = o.y + v.y;
  o.w = o.z + v.z;
  if (base + 3 < n) {
    *(int4*)&rp[base] = o;
    *(int4*)&cnt_c[base] = o;   // cursor = absolute row start
  } else {
    if (base + 0 < n) { rp[base + 0] = o.x; cnt_c[base + 0] = o.x; }
    if (base + 1 < n) { rp[base + 1] = o.y; cnt_c[base + 1] = o.y; }
    if (base + 2 < n) { rp[base + 2] = o.z; cnt_c[base + 2] = o.z; }
    if (base + 3 < n) { rp[base + 3] = o.w; cnt_c[base + 3] = o.w; }
  }
}

// ---------- fill merged CSR, 1 edge/thread (best measured occupancy) ----------
__global__ void fill_k(const int* __restrict__ e_src, const int* __restrict__ e_dst, int E,
                       const int* __restrict__ c_src, const int* __restrict__ c_dst, int EC,
                       int* __restrict__ cur, int* __restrict__ csr) {
  int i = blockIdx.x * NT + threadIdx.x;
  if (i < E) {
    csr[atomicAdd(&cur[e_dst[i]], 1)] = e_src[i];
  } else if (i < E + EC) {
    int j = i - E;
    csr[atomicAdd(&cur[c_dst[j]], 1)] = c_src[j] | CTRL_FLAG;
  }
}

// ---------- x fp32 -> bf16 ----------
__global__ void convx_k(const float* __restrict__ x, ushort* __restrict__ xh, int total4) {
  int i = blockIdx.x * NT + threadIdx.x;
  if (i < total4) {
    float4 v = ((const float4*)x)[i];
    ushort4 o;
    o.x = f2bf(v.x); o.y = f2bf(v.y); o.z = f2bf(v.z); o.w = f2bf(v.w);
    ((ushort4*)xh)[i] = o;
  }
}

// ---------- W fp32 [l][k][c] -> bf16 transposed wT[l][c][k] ----------
__global__ void convw_k(const float* __restrict__ Wc, const float* __restrict__ Wt,
                        ushort* __restrict__ wT) {
  int gid = blockIdx.x * NT + threadIdx.x;
  int l = gid >> 14, rem = gid & 16383;
  int c = rem >> 7, k = rem & 127;
  const float* W = (l < 4) ? (Wc + (size_t)l * 16384) : (Wt + (size_t)(l - 4) * 16384);
  wT[gid] = f2bf(W[k * DFEAT + c]);
}

// ---------- 8-wide chunk: shuffle src+signed-weight, 8 parallel row loads, dual-acc FMA ----------
__device__ inline void gchunk(const ushort* __restrict__ xh, int c4, int sv, float wsv, int k,
                              float& a0, float& a1, float& a2, float& a3,
                              float& b0, float& b1, float& b2, float& b3) {
  int s[8]; float w[8];
#pragma unroll
  for (int j = 0; j < 8; j++) {
    s[j] = __shfl(sv, k + j, 32);
    w[j] = __shfl(wsv, k + j, 32);
  }
  uint2 r[8];
#pragma unroll
  for (int j = 0; j < 8; j++) r[j] = *(const uint2*)&xh[(size_t)s[j] * DFEAT + c4];
#pragma unroll
  for (int j = 0; j < 8; j++) {
    float wa = fmaxf(w[j], 0.f);      // conv edges carry +w
    float wb = fmaxf(-w[j], 0.f);     // ctrl edges carry -w
    float e0 = __uint_as_float(r[j].x << 16);
    float e1 = __uint_as_float(r[j].x & 0xffff0000u);
    float e2 = __uint_as_float(r[j].y << 16);
    float e3 = __uint_as_float(r[j].y & 0xffff0000u);
    a0 = fmaf(wa, e0, a0); a1 = fmaf(wa, e1, a1);
    a2 = fmaf(wa, e2, a2); a3 = fmaf(wa, e3, a3);
    b0 = fmaf(wb, e0, b0); b1 = fmaf(wb, e1, b1);
    b2 = fmaf(wb, e2, b2); b3 = fmaf(wb, e3, b3);
  }
}

// ---------- merged-CSR aggregate, 2 nodes per 32-lane group (2x MLP) ----------
__global__ __launch_bounds__(256) void aggregate5_k(
    const ushort* __restrict__ xh,
    const int* __restrict__ rp, const int* __restrict__ cs,
    const float* __restrict__ dall,
    ushort* __restrict__ aggc, ushort* __restrict__ aggt, int n, int etot) {
  int grp = threadIdx.x >> 5;           // 0..7
  int lane = threadIdx.x & 31;
  int c4 = lane << 2;
  int node0 = blockIdx.x * 16 + grp * 2;
  if (node0 >= n) return;
  int node1 = node0 + 1;
  bool h1 = node1 < n;

  int r0 = rp[node0], r1 = rp[node0 + 1];
  int r2 = h1 ? rp[node0 + 2] : r1;
  int deg0 = r1 - r0, deg1 = r2 - r1;

  float dc0 = dall[node0], dt0 = dall[n + node0];
  float dc1 = h1 ? dall[node1] : 0.f, dt1 = h1 ? dall[n + node1] : 0.f;

  uint2 sv0 = *(const uint2*)&xh[(size_t)node0 * DFEAT + c4];
  uint2 sv1 = h1 ? *(const uint2*)&xh[(size_t)node1 * DFEAT + c4] : make_uint2(0, 0);
  float x00 = __uint_as_float(sv0.x << 16), x01 = __uint_as_float(sv0.x & 0xffff0000u);
  float x02 = __uint_as_float(sv0.y << 16), x03 = __uint_as_float(sv0.y & 0xffff0000u);
  float x10 = __uint_as_float(sv1.x << 16), x11 = __uint_as_float(sv1.x & 0xffff0000u);
  float x12 = __uint_as_float(sv1.y << 16), x13 = __uint_as_float(sv1.y & 0xffff0000u);

  float a0 = dc0 * x00, a1 = dc0 * x01, a2 = dc0 * x02, a3 = dc0 * x03;  // node0 conv
  float b0 = dt0 * x00, b1 = dt0 * x01, b2 = dt0 * x02, b3 = dt0 * x03;  // node0 ctrl
  float c0 = dc1 * x10, c1 = dc1 * x11, c2 = dc1 * x12, c3 = dc1 * x13;  // node1 conv
  float d0 = dt1 * x10, d1 = dt1 * x11, d2 = dt1 * x12, d3 = dt1 * x13;  // node1 ctrl

  int maxdeg = max(deg0, deg1);
  for (int p = 0; p < maxdeg; p += 32) {
    int mm0 = deg0 - p;                 // may be <=0 or >32
    int mm1 = deg1 - p;
    // clamped cs fetch for both nodes (invalid lanes read a safe address, weight 0)
    int q0 = r0 + p + min(lane, mm0 - 1);
    q0 = min(max(q0, 0), etot - 1);
    int q1 = r1 + p + min(lane, mm1 - 1);
    q1 = min(max(q1, 0), etot - 1);
    int v0 = cs[q0];
    int v1 = cs[q1];
    int s0v = min(v0 & SRC_MASK, n - 1);
    int s1v = min(v1 & SRC_MASK, n - 1);
    int f0 = (v0 >> 30) & 1;
    int f1 = (v1 >> 30) & 1;
    float w0 = dall[s0v + f0 * n];      // single computed-address weight load
    float w1 = dall[s1v + f1 * n];
    float ws0 = (lane < mm0) ? (f0 ? -w0 : w0) : 0.f;
    float ws1 = (lane < mm1) ? (f1 ? -w1 : w1) : 0.f;

    int cap = min(max(mm0, mm1), 32);
    for (int k = 0; k < cap; k += 8) {
      if (k < mm0) gchunk(xh, c4, s0v, ws0, k, a0, a1, a2, a3, b0, b1, b2, b3);
      if (k < mm1) gchunk(xh, c4, s1v, ws1, k, c0, c1, c2, c3, d0, d1, d2, d3);
    }
  }

  ushort4 ha, hb;
  ha.x = f2bf(dc0 * a0); ha.y = f2bf(dc0 * a1); ha.z = f2bf(dc0 * a2); ha.w = f2bf(dc0 * a3);
  hb.x = f2bf(dt0 * b0); hb.y = f2bf(dt0 * b1); hb.z = f2bf(dt0 * b2); hb.w = f2bf(dt0 * b3);
  *(ushort4*)&aggc[(size_t)node0 * DFEAT + c4] = ha;
  *(ushort4*)&aggt[(size_t)node0 * DFEAT + c4] = hb;
  if (h1) {
    ushort4 hc, hd;
    hc.x = f2bf(dc1 * c0); hc.y = f2bf(dc1 * c1); hc.z = f2bf(dc1 * c2); hc.w = f2bf(dc1 * c3);
    hd.x = f2bf(dt1 * d0); hd.y = f2bf(dt1 * d1); hd.z = f2bf(dt1 * d2); hd.w = f2bf(dt1 * d3);
    *(ushort4*)&aggc[(size_t)node1 * DFEAT + c4] = hc;
    *(ushort4*)&aggt[(size_t)node1 * DFEAT + c4] = hd;
  }
}

// ---------- fused K=256 GEMM, one 32KB XOR-swizzled W tile at a time (4 blocks/CU) ----------
// Phase 1: stage Wc, MFMA over conv half; barrier; Phase 2: stage Wt, MFMA ctrl half.
// Operand-swapped mfma -> packed ushort4/float4 row-major stores.
__global__ __launch_bounds__(256, 4) void gemmf_k(
    const ushort* __restrict__ ac, const ushort* __restrict__ at,
    const ushort* __restrict__ wTc, const ushort* __restrict__ wTt,
    const float* __restrict__ bc, const float* __restrict__ bt,
    float* __restrict__ outf, ushort* __restrict__ outh, int n, int last) {
  __shared__ __align__(16) ushort Bs[DFEAT * DFEAT];   // 32 KB, XOR-swizzled cols
  __shared__ float bias[DFEAT];
  int tid = threadIdx.x;

  int wave = tid >> 6, lane = tid & 63;
  int m = lane & 15, q = lane >> 4;
  int row0 = blockIdx.x * GEMM_ROWS + wave * 32;
  int rA = min(row0 + m, n - 1);
  int rB = min(row0 + 16 + m, n - 1);

  f32x4 zero4 = {0.f, 0.f, 0.f, 0.f};
  f32x4 acc0[8], acc1[8];
#pragma unroll
  for (int i = 0; i < 8; i++) { acc0[i] = zero4; acc1[i] = zero4; }

#pragma unroll
  for (int half = 0; half < 2; half++) {
    const ushort* wsrc = half ? wTt : wTc;
    const ushort* A    = half ? at : ac;
    if (half) __syncthreads();          // everyone done reading Bs before restage
#pragma unroll
    for (int it = 0; it < 8; it++) {
      int idx = tid + it * NT;          // 128 rows x 16 uint4
      int c = idx >> 4, i = idx & 15;
      int colu = (i * 8) ^ ((c & 7) << 3);
      *(uint4*)&Bs[c * DFEAT + colu] = *(const uint4*)&wsrc[c * DFEAT + i * 8];
    }
    if (half == 0 && tid < DFEAT) bias[tid] = bc[tid] + bt[tid];
    __syncthreads();

#pragma unroll
    for (int ks = 0; ks < 4; ks++) {
      int ko = ks * 32 + q * 8;
      union { uint4 u; s8v s; } uA, uB;
      uA.u = *(const uint4*)&A[(size_t)rA * DFEAT + ko];
      uB.u = *(const uint4*)&A[(size_t)rB * DFEAT + ko];
#pragma unroll
      for (int c8 = 0; c8 < 8; c8++) {
        int row = c8 * 16 + m;
        s8v bf = *(const s8v*)&Bs[row * DFEAT + (ko ^ ((row & 7) << 3))];
        acc0[c8] = __builtin_amdgcn_mfma_f32_16x16x32_bf16(bf, uA.s, acc0[c8], 0, 0, 0);
        acc1[c8] = __builtin_amdgcn_mfma_f32_16x16x32_bf16(bf, uB.s, acc1[c8], 0, 0, 0);
      }
    }
  }

#pragma unroll
  for (int sub = 0; sub < 2; sub++) {
    int orow = row0 + sub * 16 + m;
    if (orow < n) {
#pragma unroll
      for (int c8 = 0; c8 < 8; c8++) {
        f32x4 a = sub ? acc1[c8] : acc0[c8];
        int col = c8 * 16 + q * 4;
        float4 bv = *(const float4*)&bias[col];
        float o0 = a[0] + bv.x, o1 = a[1] + bv.y, o2 = a[2] + bv.z, o3 = a[3] + bv.w;
        if (last) {
          *(float4*)&outf[(size_t)orow * DFEAT + col] = make_float4(o0, o1, o2, o3);
        } else {
          ushort4 h;
          h.x = f2bf(fmaxf(o0, 0.f));
          h.y = f2bf(fmaxf(o1, 0.f));
          h.z = f2bf(fmaxf(o2, 0.f));
          h.w = f2bf(fmaxf(o3, 0.f));
          *(ushort4*)&outh[(size_t)orow * DFEAT + col] = h;
        }
      }
    }
  }
}

extern "C" void kernel_launch(void* const* d_in, const int* in_sizes, int n_in,
                              void* d_out, int out_size, void* d_ws, size_t ws_size,
                              hipStream_t stream) {
  const float* x0 = (const float*)d_in[0];
  const int*   ei = (const int*)d_in[1];
  const int*   ci = (const int*)d_in[2];
  const float* Wc = (const float*)d_in[3];
  const float* bc = (const float*)d_in[4];
  const float* Wt = (const float*)d_in[5];
  const float* bt = (const float*)d_in[6];
  float* out = (float*)d_out;

  int n  = in_sizes[0] / DFEAT;     // 100000
  int E  = in_sizes[1] / 2;         // 600000
  int EC = in_sizes[2] / 2;         // 200000
  int etot = E + EC;

  const int* e_src = ei;
  const int* e_dst = ei + E;
  const int* c_src = ci;
  const int* c_dst = ci + EC;

  char* p = (char*)d_ws;
  ushort* agg_c = (ushort*)p; p += (size_t)n * DFEAT * 2;
  ushort* agg_t = (ushort*)p; p += (size_t)n * DFEAT * 2;
  ushort* xh  = (ushort*)p; p += (size_t)n * DFEAT * 2;
  ushort* wT  = (ushort*)p; p += (size_t)8 * DFEAT * DFEAT * 2;
  float* dall = (float*)p; p += (size_t)2 * n * 4;
  int* cnt_c = (int*)p; p += (size_t)n * 4;     // histogram -> cursor
  int* cnt_t = (int*)p; p += (size_t)n * 4;     // histogram
  int* rp    = (int*)p; p += (size_t)(n + 1) * 4;
  int* csr   = (int*)p; p += (size_t)etot * 4;
  int* bsum  = (int*)p;

  int nb_n    = (n + NT - 1) / NT;
  int nb_node = (n + 15) / 16;
  int nb_gemm = (n + GEMM_ROWS - 1) / GEMM_ROWS;
  int nb_scan = (n + SCAN_ELEMS - 1) / SCAN_ELEMS;

  // ---- build merged CSR + dinv once per launch ----
  zero_k<<<(2 * n + NT - 1) / NT, NT, 0, stream>>>(cnt_c, 2 * n);
  hist2_k<<<(etot + NT - 1) / NT, NT, 0, stream>>>(e_dst, E, c_dst, EC, cnt_c, cnt_t);
  dinv2_k<<<nb_n, NT, 0, stream>>>(cnt_c, cnt_t, dall, n);
  scan_partial_m<<<nb_scan, NT, 0, stream>>>(cnt_c, cnt_t, n, bsum);
  scan_offsets_m<<<1, NT, 0, stream>>>(bsum, nb_scan, rp, n);
  scan_final_m<<<nb_scan, NT, 0, stream>>>(cnt_c, cnt_t, n, bsum, rp);
  fill_k<<<(etot + NT - 1) / NT, NT, 0, stream>>>(e_src, e_dst, E, c_src, c_dst, EC,
                                                  cnt_c, csr);

  // ---- bf16 conversions (gathers stay narrow: 256B/row) ----
  convx_k<<<(n * 32 + NT - 1) / NT, NT, 0, stream>>>(x0, xh, n * 32);
  convw_k<<<(8 * DFEAT * DFEAT) / NT, NT, 0, stream>>>(Wc, Wt, wT);

  // ---- layers: merged-CSR dual-node aggregate, then single fused K=256 GEMM ----
  for (int i = 0; i < 4; i++) {
    aggregate5_k<<<nb_node, NT, 0, stream>>>(xh, rp, csr, dall, agg_c, agg_t, n, etot);
    gemmf_k<<<nb_gemm, NT, 0, stream>>>(agg_c, agg_t,
                                        wT + (size_t)i * DFEAT * DFEAT,
                                        wT + (size_t)(4 + i) * DFEAT * DFEAT,
                                        bc + i * DFEAT, bt + i * DFEAT,
                                        out, xh, n, (i == 3) ? 1 : 0);
  }
}